// Round 3
// baseline (4851.902 us; speedup 1.0000x reference)
//
#include <hip/hip_runtime.h>

#define NQ   32768
#define NE   8192
#define DIM  256
#define HWsz 1024
#define MARGIN 8e-4f
#define TSEL_CAP 32

typedef __attribute__((ext_vector_type(8))) short short8;
typedef __attribute__((ext_vector_type(4))) float f32x4;

#define GLDS16(gp, lp) __builtin_amdgcn_global_load_lds( \
    (const __attribute__((address_space(1))) unsigned int*)(gp), \
    (__attribute__((address_space(3))) unsigned int*)(lp), 16, 0, 0)

static __device__ inline unsigned short f2bf(float f) {
  unsigned int u = __float_as_uint(f);
  unsigned int r = (u + 0x7fff + ((u >> 16) & 1)) >> 16;
  return (unsigned short)r;
}

// ---------- se[c] = sum(emb[c,:]^2) ----------
__global__ __launch_bounds__(256) void k_se(const float* __restrict__ emb,
                                            float* __restrict__ se) {
  int w = threadIdx.x >> 6;
  int l = threadIdx.x & 63;
  int r = blockIdx.x * 4 + w;
  float4 v = *(const float4*)(emb + (size_t)r * DIM + l * 4);
  float s = (v.x * v.x + v.y * v.y) + (v.z * v.z + v.w * v.w);
  #pragma unroll
  for (int m = 32; m >= 1; m >>= 1) s += __shfl_xor(s, m);
  if (l == 0) se[r] = s;
}

// ---------- s2[n] = sum over channels of z^2 ----------
__global__ __launch_bounds__(256) void k_s2(const float* __restrict__ z,
                                            float* __restrict__ s2) {
  __shared__ float red[4][64];
  int blk = blockIdx.x;
  int b = blk >> 4;
  int hw0 = (blk & 15) << 6;
  int q = threadIdx.x & 63;
  int p = threadIdx.x >> 6;
  const float* zp = z + (size_t)(b * DIM + p * 64) * HWsz + hw0 + q;
  float s = 0.f;
  #pragma unroll 4
  for (int c = 0; c < 64; ++c) {
    float v = zp[(size_t)c * HWsz];
    s = fmaf(v, v, s);
  }
  red[p][q] = s;
  __syncthreads();
  if (threadIdx.x < 64) {
    s2[blk * 64 + q] = (red[0][q] + red[1][q]) + (red[2][q] + red[3][q]);
  }
}

// ---------- emb fp32 [c][k] -> bf16 tile-image ebf ----------
// chunk gid: t32=gid>>10, w=gid&1023 -> cf=w>>9, kk=(w>>6)&7, l=w&63
// holds emb[t32*32+cf*16+(l&15)][(l>>4)*8+kk*32 + j], j=0..7
__global__ __launch_bounds__(256) void k_ebf(const float* __restrict__ emb,
                                             unsigned short* __restrict__ ebf) {
  int gid = blockIdx.x * 256 + threadIdx.x;
  int t32 = gid >> 10;
  int wi = gid & 1023;
  int cf = wi >> 9;
  int kk = (wi >> 6) & 7;
  int l = wi & 63;
  int row = t32 * 32 + cf * 16 + (l & 15);
  int col = (l >> 4) * 8 + kk * 32;
  const float* src = emb + (size_t)row * DIM + col;
  float4 v0 = *(const float4*)(src);
  float4 v1 = *(const float4*)(src + 4);
  unsigned short o[8] = {f2bf(v0.x), f2bf(v0.y), f2bf(v0.z), f2bf(v0.w),
                         f2bf(v1.x), f2bf(v1.y), f2bf(v1.z), f2bf(v1.w)};
  *(short8*)(ebf + (size_t)gid * 8) = *(short8*)o;
}

// ---------- z [b][ch][hw] fp32 -> za [q][ch] bf16 (tiled LDS transpose) ----------
__global__ __launch_bounds__(256) void k_tr(const float* __restrict__ z,
                                            unsigned short* __restrict__ za) {
  __shared__ float lt[64][65];
  int blk = blockIdx.x;
  int b = blk >> 6;
  int r = blk & 63;
  int ch0 = (r >> 4) * 64;
  int hw0 = (r & 15) * 64;
  int tid = threadIdx.x;
  #pragma unroll
  for (int p = 0; p < 4; ++p) {
    int idx = p * 256 + tid;
    int ch = idx >> 4;
    int hc = idx & 15;
    float4 v = *(const float4*)(z + (size_t)(b * DIM + ch0 + ch) * HWsz + hw0 + hc * 4);
    lt[ch][hc * 4 + 0] = v.x;
    lt[ch][hc * 4 + 1] = v.y;
    lt[ch][hc * 4 + 2] = v.z;
    lt[ch][hc * 4 + 3] = v.w;
  }
  __syncthreads();
  #pragma unroll
  for (int p = 0; p < 2; ++p) {
    int idx = p * 256 + tid;
    int hw = idx >> 3;
    int cc = idx & 7;
    unsigned short o[8];
    #pragma unroll
    for (int j = 0; j < 8; ++j) o[j] = f2bf(lt[cc * 8 + j][hw]);
    *(short8*)(za + (size_t)((b << 10) + hw0 + hw) * DIM + ch0 + cc * 8) = *(short8*)o;
  }
}

// ---------- single MFMA pass: scores + per-32-code-tile max (bf16, round-up) ----------
// grid 512: qb = blk>>2 (256 queries), ct = blk&3 (2048 codes = 64 tiles of 32)
// swapped operands: D[c][q], lane holds q=lane&15, c=(lane>>4)*4+r
__global__ __launch_bounds__(256, 2) void k_score(const unsigned short* __restrict__ za,
                                                  const unsigned short* __restrict__ ebf,
                                                  unsigned short* __restrict__ tmax) {
  __shared__ __align__(16) char ebt[2][16384];
  const int tid = threadIdx.x, lane = tid & 63, w = tid >> 6;
  const int qb = blockIdx.x >> 2, ct = blockIdx.x & 3;
  const int q0w = qb * 256 + w * 64;
  const char* ebase = (const char*)ebf + (size_t)ct * 64 * 16384;

  short8 a[4][8];
  #pragma unroll
  for (int f = 0; f < 4; ++f)
    #pragma unroll
    for (int kk = 0; kk < 8; ++kk)
      a[f][kk] = *(const short8*)(za + (size_t)(q0w + f * 16 + (lane & 15)) * DIM
                                  + (lane >> 4) * 8 + kk * 32);

  // prologue: stage tile 0 into buffer 0
  #pragma unroll
  for (int j = 0; j < 4; ++j)
    GLDS16(ebase + (j * 256 + tid) * 16, &ebt[0][(j * 256 + tid) * 16]);

  int cur = 0;
  for (int t = 0; t < 64; ++t) {
    if (t == 0) asm volatile("s_waitcnt vmcnt(0)" ::: "memory");
    else        asm volatile("s_waitcnt vmcnt(1)" ::: "memory");
    __builtin_amdgcn_s_barrier();
    __builtin_amdgcn_sched_barrier(0);
    if (t < 63) {
      const char* src = ebase + (size_t)(t + 1) * 16384;
      #pragma unroll
      for (int j = 0; j < 4; ++j)
        GLDS16(src + (j * 256 + tid) * 16, &ebt[cur ^ 1][(j * 256 + tid) * 16]);
    }
    __builtin_amdgcn_sched_barrier(0);

    f32x4 acc0[4], acc1[4];
    #pragma unroll
    for (int f = 0; f < 4; ++f) {
      acc0[f] = (f32x4){0.f, 0.f, 0.f, 0.f};
      acc1[f] = (f32x4){0.f, 0.f, 0.f, 0.f};
    }
    #pragma unroll
    for (int kk = 0; kk < 8; ++kk) {
      short8 b0 = *(const short8*)&ebt[cur][kk * 1024 + lane * 16];
      short8 b1 = *(const short8*)&ebt[cur][8192 + kk * 1024 + lane * 16];
      #pragma unroll
      for (int f = 0; f < 4; ++f) {
        acc0[f] = __builtin_amdgcn_mfma_f32_16x16x32_bf16(b0, a[f][kk], acc0[f], 0, 0, 0);
        acc1[f] = __builtin_amdgcn_mfma_f32_16x16x32_bf16(b1, a[f][kk], acc1[f], 0, 0, 0);
      }
    }
    // per-query max over this 32-code tile
    float tm[4];
    #pragma unroll
    for (int f = 0; f < 4; ++f) {
      float v = fmaxf(fmaxf(fmaxf(acc0[f][0], acc0[f][1]), fmaxf(acc0[f][2], acc0[f][3])),
                      fmaxf(fmaxf(acc1[f][0], acc1[f][1]), fmaxf(acc1[f][2], acc1[f][3])));
      v = fmaxf(v, __shfl_xor(v, 16));
      v = fmaxf(v, __shfl_xor(v, 32));
      tm[f] = v;
    }
    int g = lane >> 4;
    float sel = g == 0 ? tm[0] : (g == 1 ? tm[1] : (g == 2 ? tm[2] : tm[3]));
    // bf16 round-toward-+inf (conservative tile max)
    unsigned int u = __float_as_uint(sel);
    unsigned short h = (unsigned short)(u >> 16);
    if ((u & 0xffffu) && !(u >> 31)) ++h;
    tmax[(size_t)(ct * 64 + t) * NQ + qb * 256 + w * 64 + lane] = h;
    cur ^= 1;
  }
}

// ---------- per-query: global max over tiles, select tiles within margin ----------
__global__ __launch_bounds__(256) void k_collect(const unsigned short* __restrict__ tmax,
                                                 int* __restrict__ tcnt,
                                                 int* __restrict__ tsel) {
  int q = blockIdx.x * 256 + threadIdx.x;
  float m = -3.4028235e38f;
  for (int t = 0; t < 256; ++t) {
    unsigned int u = (unsigned int)tmax[(size_t)t * NQ + q] << 16;
    m = fmaxf(m, __uint_as_float(u));
  }
  float thr = m - MARGIN;
  int cnt = 0;
  for (int t = 0; t < 256; ++t) {
    unsigned int u = (unsigned int)tmax[(size_t)t * NQ + q] << 16;
    if (__uint_as_float(u) > thr) {
      if (cnt < TSEL_CAP) tsel[(size_t)q * TSEL_CAP + cnt] = t;
      ++cnt;
    }
  }
  tcnt[q] = cnt;
}

// ---------- exact fp32 rescore of selected tiles (wave per query) ----------
__global__ __launch_bounds__(256) void k_rescore(const float* __restrict__ z,
                                                 const float* __restrict__ emb,
                                                 const float* __restrict__ se,
                                                 const float* __restrict__ s2,
                                                 const int* __restrict__ tcnt,
                                                 const int* __restrict__ tsel,
                                                 int* __restrict__ best) {
  int q = blockIdx.x * 4 + (threadIdx.x >> 6);
  int lane = threadIdx.x & 63;
  int b = q >> 10;
  int hw = q & 1023;
  float zr[4];
  #pragma unroll
  for (int j = 0; j < 4; ++j)
    zr[j] = z[(size_t)((b << 8) + lane * 4 + j) * HWsz + hw];
  float s2q = s2[q];
  int n = tcnt[q];
  bool full = (n <= 0) || (n > TSEL_CAP);
  int ntiles = full ? 256 : n;
  float bd = 3.4028235e38f;
  int bi = 0x7fffffff;
  for (int i = 0; i < ntiles; ++i) {
    int t = full ? i : tsel[(size_t)q * TSEL_CAP + i];
    #pragma unroll 4
    for (int k = 0; k < 32; ++k) {
      int c = t * 32 + k;
      float4 e = *(const float4*)(emb + (size_t)c * DIM + lane * 4);
      float p = fmaf(zr[0], e.x, fmaf(zr[1], e.y, fmaf(zr[2], e.z, zr[3] * e.w)));
      #pragma unroll
      for (int m = 1; m <= 32; m <<= 1) p += __shfl_xor(p, m);
      float tt = s2q + se[c];
      float d = tt - 2.0f * p;
      if (d < bd || (d == bd && c < bi)) { bd = d; bi = c; }
    }
  }
  if (lane == 0) best[q] = bi;
}

// ---------- output writer: z_q (straight-through) + indices as float ----------
__global__ __launch_bounds__(256) void k_out(const float* __restrict__ z,
                                             const float* __restrict__ emb,
                                             const int* __restrict__ best,
                                             float* __restrict__ out) {
  int i = blockIdx.x * 256 + threadIdx.x;
  if (i < NQ * DIM) {
    int bb = i >> 18;
    int c  = (i >> 10) & 255;
    int hw = i & 1023;
    int n  = (bb << 10) + hw;
    float zv = z[i];
    float evv = emb[(size_t)best[n] * DIM + c];
    out[i] = zv + (evv - zv);
  } else {
    int n = i - NQ * DIM;
    out[i] = (float)best[n];
  }
}

extern "C" void kernel_launch(void* const* d_in, const int* in_sizes, int n_in,
                              void* d_out, int out_size, void* d_ws, size_t ws_size,
                              hipStream_t stream) {
  const float* z   = (const float*)d_in[0];
  const float* emb = (const float*)d_in[1];
  float* out = (float*)d_out;

  char* ws = (char*)d_ws;
  float* se   = (float*)(ws + 0);                  //  32 KB
  float* s2   = (float*)(ws + 32768);              // 128 KB
  int*   best = (int*)  (ws + 163840);             // 128 KB
  int*   tcnt = (int*)  (ws + 294912);             // 128 KB
  int*   tsel = (int*)  (ws + 425984);             //   4 MB
  unsigned short* tmax = (unsigned short*)(ws + 4620288);   // 16 MB
  unsigned short* za   = (unsigned short*)(ws + 21397504);  // 16 MB
  unsigned short* ebf  = (unsigned short*)(ws + 38174720);  //  4 MB

  k_se     <<<NE / 4, 256, 0, stream>>>(emb, se);
  k_s2     <<<NQ / 64, 256, 0, stream>>>(z, s2);
  k_ebf    <<<1024, 256, 0, stream>>>(emb, ebf);
  k_tr     <<<2048, 256, 0, stream>>>(z, za);
  k_score  <<<512, 256, 0, stream>>>(za, ebf, tmax);
  k_collect<<<NQ / 256, 256, 0, stream>>>(tmax, tcnt, tsel);
  k_rescore<<<NQ / 4, 256, 0, stream>>>(z, emb, se, s2, tcnt, tsel, best);
  k_out    <<<(NQ * DIM + NQ) / 256, 256, 0, stream>>>(z, emb, best, out);
}

// Round 4
// 373.140 us; speedup vs baseline: 13.0029x; 13.0029x over previous
//
#include <hip/hip_runtime.h>

#define NQ   32768
#define NE   8192
#define DIM  256
#define HWsz 1024
#define MARGIN 4e-4f
#define CAP  32

typedef __attribute__((ext_vector_type(8))) short short8;
typedef __attribute__((ext_vector_type(4))) float f32x4;

#define GLDS16(gp, lp) __builtin_amdgcn_global_load_lds( \
    (const __attribute__((address_space(1))) unsigned int*)(gp), \
    (__attribute__((address_space(3))) unsigned int*)(lp), 16, 0, 0)

static __device__ inline unsigned short f2bf(float f) {
  unsigned int u = __float_as_uint(f);
  unsigned int r = (u + 0x7fff + ((u >> 16) & 1)) >> 16;
  return (unsigned short)r;
}

// ---------- se[c] = sum(emb[c,:]^2) ----------
__global__ __launch_bounds__(256) void k_se(const float* __restrict__ emb,
                                            float* __restrict__ se) {
  int w = threadIdx.x >> 6;
  int l = threadIdx.x & 63;
  int r = blockIdx.x * 4 + w;
  float4 v = *(const float4*)(emb + (size_t)r * DIM + l * 4);
  float s = (v.x * v.x + v.y * v.y) + (v.z * v.z + v.w * v.w);
  #pragma unroll
  for (int m = 32; m >= 1; m >>= 1) s += __shfl_xor(s, m);
  if (l == 0) se[r] = s;
}

// ---------- s2[n] = sum over channels of z^2 ----------
__global__ __launch_bounds__(256) void k_s2(const float* __restrict__ z,
                                            float* __restrict__ s2) {
  __shared__ float red[4][64];
  int blk = blockIdx.x;
  int b = blk >> 4;
  int hw0 = (blk & 15) << 6;
  int q = threadIdx.x & 63;
  int p = threadIdx.x >> 6;
  const float* zp = z + (size_t)(b * DIM + p * 64) * HWsz + hw0 + q;
  float s = 0.f;
  #pragma unroll 4
  for (int c = 0; c < 64; ++c) {
    float v = zp[(size_t)c * HWsz];
    s = fmaf(v, v, s);
  }
  red[p][q] = s;
  __syncthreads();
  if (threadIdx.x < 64) {
    s2[blk * 64 + q] = (red[0][q] + red[1][q]) + (red[2][q] + red[3][q]);
  }
}

// ---------- emb fp32 [c][k] -> bf16 tile-image ebf (same layout as round 2/3) ----------
__global__ __launch_bounds__(256) void k_ebf(const float* __restrict__ emb,
                                             unsigned short* __restrict__ ebf) {
  int gid = blockIdx.x * 256 + threadIdx.x;
  int t32 = gid >> 10;
  int wi = gid & 1023;
  int cf = wi >> 9;
  int kk = (wi >> 6) & 7;
  int l = wi & 63;
  int row = t32 * 32 + cf * 16 + (l & 15);
  int col = (l >> 4) * 8 + kk * 32;
  const float* src = emb + (size_t)row * DIM + col;
  float4 v0 = *(const float4*)(src);
  float4 v1 = *(const float4*)(src + 4);
  unsigned short o[8] = {f2bf(v0.x), f2bf(v0.y), f2bf(v0.z), f2bf(v0.w),
                         f2bf(v1.x), f2bf(v1.y), f2bf(v1.z), f2bf(v1.w)};
  *(short8*)(ebf + (size_t)gid * 8) = *(short8*)o;
}

// ---------- z [b][ch][hw] fp32 -> za [q][ch] bf16 (tiled LDS transpose) ----------
__global__ __launch_bounds__(256) void k_tr(const float* __restrict__ z,
                                            unsigned short* __restrict__ za) {
  __shared__ float lt[64][65];
  int blk = blockIdx.x;
  int b = blk >> 6;
  int r = blk & 63;
  int ch0 = (r >> 4) * 64;
  int hw0 = (r & 15) * 64;
  int tid = threadIdx.x;
  #pragma unroll
  for (int p = 0; p < 4; ++p) {
    int idx = p * 256 + tid;
    int ch = idx >> 4;
    int hc = idx & 15;
    float4 v = *(const float4*)(z + (size_t)(b * DIM + ch0 + ch) * HWsz + hw0 + hc * 4);
    lt[ch][hc * 4 + 0] = v.x;
    lt[ch][hc * 4 + 1] = v.y;
    lt[ch][hc * 4 + 2] = v.z;
    lt[ch][hc * 4 + 3] = v.w;
  }
  __syncthreads();
  #pragma unroll
  for (int p = 0; p < 2; ++p) {
    int idx = p * 256 + tid;
    int hw = idx >> 3;
    int cc = idx & 7;
    unsigned short o[8];
    #pragma unroll
    for (int j = 0; j < 8; ++j) o[j] = f2bf(lt[cc * 8 + j][hw]);
    *(short8*)(za + (size_t)((b << 10) + hw0 + hw) * DIM + ch0 + cc * 8) = *(short8*)o;
  }
}

// ---------- pass 1: per-query max of approx scores over this block's 1024 codes ----------
// grid 2048: qb = blk>>3 (128 queries), ct = blk&7 (1024 codes = 32 tiles of 32)
// swapped operands: D[c][q]; wave owns 32 queries (2 fragments)
__global__ __launch_bounds__(256, 4) void k_max(const unsigned short* __restrict__ za,
                                                const unsigned short* __restrict__ ebf,
                                                float* __restrict__ qbest) {
  __shared__ __align__(16) char ebt[2][16384];
  const int tid = threadIdx.x, lane = tid & 63, w = tid >> 6;
  const int qb = blockIdx.x >> 3, ct = blockIdx.x & 7;
  const int q0w = qb * 128 + w * 32;
  const char* ebase = (const char*)ebf + (size_t)ct * 32 * 16384;

  short8 a[2][8];
  #pragma unroll
  for (int f = 0; f < 2; ++f)
    #pragma unroll
    for (int kk = 0; kk < 8; ++kk)
      a[f][kk] = *(const short8*)(za + (size_t)(q0w + f * 16 + (lane & 15)) * DIM
                                  + (lane >> 4) * 8 + kk * 32);

  float runmax[2] = {-3.4028235e38f, -3.4028235e38f};

  #pragma unroll
  for (int j = 0; j < 4; ++j)
    GLDS16(ebase + (j * 256 + tid) * 16, &ebt[0][(j * 256 + tid) * 16]);
  asm volatile("s_waitcnt vmcnt(0)" ::: "memory");
  __builtin_amdgcn_s_barrier();

  int cur = 0;
  for (int t = 0; t < 32; ++t) {
    if (t < 31) {
      const char* src = ebase + (size_t)(t + 1) * 16384;
      #pragma unroll
      for (int j = 0; j < 4; ++j)
        GLDS16(src + (j * 256 + tid) * 16, &ebt[cur ^ 1][(j * 256 + tid) * 16]);
    }
    __builtin_amdgcn_sched_barrier(0);

    f32x4 acc0[2], acc1[2];
    #pragma unroll
    for (int f = 0; f < 2; ++f) {
      acc0[f] = (f32x4){0.f, 0.f, 0.f, 0.f};
      acc1[f] = (f32x4){0.f, 0.f, 0.f, 0.f};
    }
    #pragma unroll
    for (int kk = 0; kk < 8; ++kk) {
      short8 b0 = *(const short8*)&ebt[cur][kk * 1024 + lane * 16];
      short8 b1 = *(const short8*)&ebt[cur][8192 + kk * 1024 + lane * 16];
      #pragma unroll
      for (int f = 0; f < 2; ++f) {
        acc0[f] = __builtin_amdgcn_mfma_f32_16x16x32_bf16(b0, a[f][kk], acc0[f], 0, 0, 0);
        acc1[f] = __builtin_amdgcn_mfma_f32_16x16x32_bf16(b1, a[f][kk], acc1[f], 0, 0, 0);
      }
    }
    #pragma unroll
    for (int f = 0; f < 2; ++f) {
      float v = fmaxf(fmaxf(fmaxf(acc0[f][0], acc0[f][1]), fmaxf(acc0[f][2], acc0[f][3])),
                      fmaxf(fmaxf(acc1[f][0], acc1[f][1]), fmaxf(acc1[f][2], acc1[f][3])));
      runmax[f] = fmaxf(runmax[f], v);
    }
    asm volatile("s_waitcnt vmcnt(0)" ::: "memory");
    __builtin_amdgcn_s_barrier();
    cur ^= 1;
  }
  #pragma unroll
  for (int f = 0; f < 2; ++f) {
    float v = runmax[f];
    v = fmaxf(v, __shfl_xor(v, 16));
    v = fmaxf(v, __shfl_xor(v, 32));
    if ((lane >> 4) == 0)
      qbest[(size_t)ct * NQ + q0w + f * 16 + lane] = v;
  }
}

// ---------- merge: qthr = max over 8 splits - margin; reset cnt ----------
__global__ __launch_bounds__(256) void k_merge(const float* __restrict__ qbest,
                                               float* __restrict__ qthr,
                                               int* __restrict__ cnt) {
  int q = blockIdx.x * 256 + threadIdx.x;
  float m = qbest[q];
  #pragma unroll
  for (int ct = 1; ct < 8; ++ct) m = fmaxf(m, qbest[(size_t)ct * NQ + q]);
  qthr[q] = m - MARGIN;
  cnt[q] = 0;
}

// ---------- pass 2: recompute scores (bit-identical), append codes above thr ----------
__global__ __launch_bounds__(256, 4) void k_cand(const unsigned short* __restrict__ za,
                                                 const unsigned short* __restrict__ ebf,
                                                 const float* __restrict__ qthr,
                                                 int* __restrict__ cnt,
                                                 int* __restrict__ cand) {
  __shared__ __align__(16) char ebt[2][16384];
  const int tid = threadIdx.x, lane = tid & 63, w = tid >> 6;
  const int qb = blockIdx.x >> 3, ct = blockIdx.x & 7;
  const int q0w = qb * 128 + w * 32;
  const char* ebase = (const char*)ebf + (size_t)ct * 32 * 16384;

  short8 a[2][8];
  #pragma unroll
  for (int f = 0; f < 2; ++f)
    #pragma unroll
    for (int kk = 0; kk < 8; ++kk)
      a[f][kk] = *(const short8*)(za + (size_t)(q0w + f * 16 + (lane & 15)) * DIM
                                  + (lane >> 4) * 8 + kk * 32);

  float thr[2];
  #pragma unroll
  for (int f = 0; f < 2; ++f) thr[f] = qthr[q0w + f * 16 + (lane & 15)];

  #pragma unroll
  for (int j = 0; j < 4; ++j)
    GLDS16(ebase + (j * 256 + tid) * 16, &ebt[0][(j * 256 + tid) * 16]);
  asm volatile("s_waitcnt vmcnt(0)" ::: "memory");
  __builtin_amdgcn_s_barrier();

  int cur = 0;
  for (int t = 0; t < 32; ++t) {
    if (t < 31) {
      const char* src = ebase + (size_t)(t + 1) * 16384;
      #pragma unroll
      for (int j = 0; j < 4; ++j)
        GLDS16(src + (j * 256 + tid) * 16, &ebt[cur ^ 1][(j * 256 + tid) * 16]);
    }
    __builtin_amdgcn_sched_barrier(0);

    f32x4 acc0[2], acc1[2];
    #pragma unroll
    for (int f = 0; f < 2; ++f) {
      acc0[f] = (f32x4){0.f, 0.f, 0.f, 0.f};
      acc1[f] = (f32x4){0.f, 0.f, 0.f, 0.f};
    }
    #pragma unroll
    for (int kk = 0; kk < 8; ++kk) {
      short8 b0 = *(const short8*)&ebt[cur][kk * 1024 + lane * 16];
      short8 b1 = *(const short8*)&ebt[cur][8192 + kk * 1024 + lane * 16];
      #pragma unroll
      for (int f = 0; f < 2; ++f) {
        acc0[f] = __builtin_amdgcn_mfma_f32_16x16x32_bf16(b0, a[f][kk], acc0[f], 0, 0, 0);
        acc1[f] = __builtin_amdgcn_mfma_f32_16x16x32_bf16(b1, a[f][kk], acc1[f], 0, 0, 0);
      }
    }
    int cbase = ct * 1024 + t * 32 + (lane >> 4) * 4;
    #pragma unroll
    for (int f = 0; f < 2; ++f) {
      int q = q0w + f * 16 + (lane & 15);
      #pragma unroll
      for (int r = 0; r < 4; ++r) {
        if (acc0[f][r] > thr[f]) {
          int pos = atomicAdd(&cnt[q], 1);
          if (pos < CAP) cand[(size_t)q * CAP + pos] = cbase + r;
        }
        if (acc1[f][r] > thr[f]) {
          int pos = atomicAdd(&cnt[q], 1);
          if (pos < CAP) cand[(size_t)q * CAP + pos] = cbase + 16 + r;
        }
      }
    }
    asm volatile("s_waitcnt vmcnt(0)" ::: "memory");
    __builtin_amdgcn_s_barrier();
    cur ^= 1;
  }
}

// ---------- exact fp32 rescore of candidates (wave per query) ----------
__global__ __launch_bounds__(256) void k_rescore(const float* __restrict__ z,
                                                 const float* __restrict__ emb,
                                                 const float* __restrict__ se,
                                                 const float* __restrict__ s2,
                                                 const int* __restrict__ cnt,
                                                 const int* __restrict__ cand,
                                                 int* __restrict__ best) {
  int q = blockIdx.x * 4 + (threadIdx.x >> 6);
  int lane = threadIdx.x & 63;
  int b = q >> 10;
  int hw = q & 1023;
  float zr[4];
  #pragma unroll
  for (int j = 0; j < 4; ++j)
    zr[j] = z[(size_t)((b << 8) + lane * 4 + j) * HWsz + hw];
  float s2q = s2[q];
  int n = cnt[q];
  bool full = (n <= 0) || (n > CAP);
  int count = full ? NE : n;
  float bd = 3.4028235e38f;
  int bi = 0x7fffffff;
  for (int i = 0; i < count; ++i) {
    int c = full ? i : cand[(size_t)q * CAP + i];
    float4 e = *(const float4*)(emb + (size_t)c * DIM + lane * 4);
    float p = fmaf(zr[0], e.x, fmaf(zr[1], e.y, fmaf(zr[2], e.z, zr[3] * e.w)));
    #pragma unroll
    for (int m = 1; m <= 32; m <<= 1) p += __shfl_xor(p, m);
    float t = s2q + se[c];
    float d = t - 2.0f * p;
    if (d < bd || (d == bd && c < bi)) { bd = d; bi = c; }
  }
  if (lane == 0) best[q] = bi;
}

// ---------- output writer: z_q (straight-through) + indices as float ----------
__global__ __launch_bounds__(256) void k_out(const float* __restrict__ z,
                                             const float* __restrict__ emb,
                                             const int* __restrict__ best,
                                             float* __restrict__ out) {
  int i = blockIdx.x * 256 + threadIdx.x;
  if (i < NQ * DIM) {
    int bb = i >> 18;
    int c  = (i >> 10) & 255;
    int hw = i & 1023;
    int n  = (bb << 10) + hw;
    float zv = z[i];
    float evv = emb[(size_t)best[n] * DIM + c];
    out[i] = zv + (evv - zv);
  } else {
    int n = i - NQ * DIM;
    out[i] = (float)best[n];
  }
}

extern "C" void kernel_launch(void* const* d_in, const int* in_sizes, int n_in,
                              void* d_out, int out_size, void* d_ws, size_t ws_size,
                              hipStream_t stream) {
  const float* z   = (const float*)d_in[0];
  const float* emb = (const float*)d_in[1];
  float* out = (float*)d_out;

  char* ws = (char*)d_ws;
  float* se    = (float*)(ws + 0);                 //  32 KB
  float* s2    = (float*)(ws + 32768);             // 128 KB
  int*   best  = (int*)  (ws + 163840);            // 128 KB
  float* qbest = (float*)(ws + 294912);            //   1 MB (8 x NQ f32)
  float* qthr  = (float*)(ws + 1343488);           // 128 KB
  int*   cnt   = (int*)  (ws + 1474560);           // 128 KB
  int*   cand  = (int*)  (ws + 1605632);           //   4 MB (NQ x 32 i32)
  unsigned short* za  = (unsigned short*)(ws + 5799936);   // 16 MB
  unsigned short* ebf = (unsigned short*)(ws + 22577152);  //  4 MB  (total ~25.6 MB)

  k_se     <<<NE / 4, 256, 0, stream>>>(emb, se);
  k_s2     <<<NQ / 64, 256, 0, stream>>>(z, s2);
  k_ebf    <<<1024, 256, 0, stream>>>(emb, ebf);
  k_tr     <<<2048, 256, 0, stream>>>(z, za);
  k_max    <<<2048, 256, 0, stream>>>(za, ebf, qbest);
  k_merge  <<<NQ / 256, 256, 0, stream>>>(qbest, qthr, cnt);
  k_cand   <<<2048, 256, 0, stream>>>(za, ebf, qthr, cnt, cand);
  k_rescore<<<NQ / 4, 256, 0, stream>>>(z, emb, se, s2, cnt, cand, best);
  k_out    <<<(NQ * DIM + NQ) / 256, 256, 0, stream>>>(z, emb, best, out);
}